// Round 6
// baseline (714.486 us; speedup 1.0000x reference)
//
#include <hip/hip_runtime.h>
#include <math.h>
#include <float.h>

#define EPSV 1e-8f
constexpr int D = 64;

typedef __attribute__((ext_vector_type(8)))  short short8;
typedef __attribute__((ext_vector_type(16))) float f32x16;

static __device__ __forceinline__ unsigned short f2bf(float f) {
    unsigned u = __float_as_uint(f);
    unsigned r = u + 0x7FFFu + ((u >> 16) & 1u);   // round-to-nearest-even
    return (unsigned short)(r >> 16);
}
static __device__ __forceinline__ float bf2f(unsigned short b) {
    return __uint_as_float(((unsigned)b) << 16);
}
// fragment-ready layout: entity panel p=e>>5, k-slot q=k>>3:
//   u16 index = p*2048 + q*256 + (e&31)*8 + (k&7)
static __device__ __forceinline__ size_t fragidx(int e, int k) {
    return (size_t)(e >> 5) * 2048 + (size_t)(k >> 3) * 256 + (e & 31) * 8 + (k & 7);
}

// ---------------------------------------------------------------------------
// bitpack: stream the 1.07 GB int mask once at HBM BW -> 32 MB bit matrix
//   bits[row][w] (u32, w = code/32); training==0 folds to all-ones.
// ---------------------------------------------------------------------------
__global__ __launch_bounds__(256) void k_bitpack(const int* __restrict__ mask,
                                                 const int* __restrict__ training,
                                                 unsigned* __restrict__ bits,
                                                 long long nseg) {
    const int t = threadIdx.x;
    const int lane = t & 63;
    const long long wid = (long long)blockIdx.x * 4 + (t >> 6);
    const long long nw = (long long)gridDim.x * 4;
    const int tr = training[0];
    for (long long s = wid; s < nseg; s += nw) {
        const int v = mask[s * 64 + lane];
        const unsigned long long b = __ballot(v != 0 || tr == 0);
        if (lane == 0) *(unsigned long long*)(bits + s * 2) = b;
    }
}

// ---------------------------------------------------------------------------
// prep: normalize codebook. cb fp32 (for gather) + double-normalized hi/lo
// bf16 fragments.
// ---------------------------------------------------------------------------
__global__ __launch_bounds__(256) void k_prep_cb(const float* __restrict__ cbin,
                                                 float* __restrict__ cb,
                                                 unsigned short* __restrict__ ch,
                                                 unsigned short* __restrict__ cl) {
    const int t = threadIdx.x;
    const int wv = t >> 6, lane = t & 63;
    const int code = blockIdx.x * 4 + wv;
    float v = cbin[(size_t)code * D + lane];
    float ss = v * v;
    #pragma unroll
    for (int off = 32; off; off >>= 1) ss += __shfl_xor(ss, off, 64);
    const float c1 = v / (sqrtf(ss) + EPSV);
    cb[(size_t)code * D + lane] = c1;
    float ss2 = c1 * c1;
    #pragma unroll
    for (int off = 32; off; off >>= 1) ss2 += __shfl_xor(ss2, off, 64);
    const float c2 = c1 / (sqrtf(ss2) + EPSV);
    const unsigned short h = f2bf(c2);
    const size_t fi = fragidx(code, lane);
    ch[fi] = h;
    cl[fi] = f2bf(c2 - bf2f(h));
}

// ---------------------------------------------------------------------------
// prep: normalize x -> xn (fp32, straight to d_out region 2) + hi/lo fragments
// ---------------------------------------------------------------------------
__global__ __launch_bounds__(256) void k_prep_x(const float* __restrict__ xin,
                                                float* __restrict__ xn,
                                                unsigned short* __restrict__ xh,
                                                unsigned short* __restrict__ xl) {
    const int t = threadIdx.x;
    const int wv = t >> 6, lane = t & 63;
    const int row = blockIdx.x * 4 + wv;
    float v = xin[(size_t)row * D + lane];
    float ss = v * v;
    #pragma unroll
    for (int off = 32; off; off >>= 1) ss += __shfl_xor(ss, off, 64);
    const float xv = v / (sqrtf(ss) + EPSV);
    xn[(size_t)row * D + lane] = xv;
    const unsigned short h = f2bf(xv);
    const size_t fi = fragidx(row, lane);
    xh[fi] = h;
    xl[fi] = f2bf(xv - bf2f(h));
}

// ---------------------------------------------------------------------------
// main: 128 rows x 128 codes per block, 4 waves (each: 32 rows x 128 codes).
// 3-term bf16 MFMA (32x32x16). dist quantized to 18 bits, packed (q<<14)|k:
// u32-min = argmin with lower-index tie-break. Track top-2 for margin flag.
// Mask now read as broadcast bit-words (L1/L2 resident), not the HBM stream.
// ---------------------------------------------------------------------------
__global__ __launch_bounds__(256, 3) void k_mfma(const unsigned short* __restrict__ xh,
                                                 const unsigned short* __restrict__ xl,
                                                 const unsigned short* __restrict__ ch,
                                                 const unsigned short* __restrict__ cl,
                                                 const unsigned* __restrict__ bits,
                                                 unsigned* __restrict__ pk1,
                                                 unsigned* __restrict__ pk2,
                                                 int K, int ncb) {
    const int t = threadIdx.x;
    const int wv = t >> 6, lane = t & 63;
    const int lh = lane >> 5, lm = lane & 31;
    const int cbk = blockIdx.x % ncb;
    const int rb  = blockIdx.x / ncb;
    const int wpr = K >> 5;                      // bit-words per row (512)

    const short8* xh8 = (const short8*)xh;
    const short8* xl8 = (const short8*)xl;
    const short8* ch8 = (const short8*)ch;
    const short8* cl8 = (const short8*)cl;

    // A fragments: 32 rows x 64 dims, hi+lo (held for the whole block)
    const int rp = rb * 4 + wv;                  // row panel of 32
    short8 ah[4], al[4];
    #pragma unroll
    for (int s = 0; s < 4; ++s) {
        const size_t ai = (size_t)rp * 256 + (s * 2 + lh) * 32 + lm;
        ah[s] = xh8[ai];
        al[s] = xl8[ai];
    }

    unsigned k1[16], k2[16];
    #pragma unroll
    for (int i = 0; i < 16; ++i) { k1[i] = 0xFFFFFFFFu; k2[i] = 0xFFFFFFFFu; }

    const int row0 = rb * 128 + wv * 32;
    const unsigned* bb = bits + (size_t)row0 * wpr + cbk * 4;

    #pragma unroll
    for (int c = 0; c < 4; ++c) {
        const int cp = cbk * 4 + c;              // code panel of 32
        // bit-words for this panel: one broadcast u32 per accumulator row
        unsigned mv[16];
        #pragma unroll
        for (int r = 0; r < 16; ++r) {
            const int lrow = (r & 3) + 8 * (r >> 2) + 4 * lh;
            mv[r] = bb[(size_t)lrow * wpr + c];
        }
        short8 bh[4], bl[4];
        #pragma unroll
        for (int s = 0; s < 4; ++s) {
            const size_t bi = (size_t)cp * 256 + (s * 2 + lh) * 32 + lm;
            bh[s] = ch8[bi];
            bl[s] = cl8[bi];
        }
        f32x16 acc;
        #pragma unroll
        for (int i = 0; i < 16; ++i) acc[i] = 0.f;
        #pragma unroll
        for (int s = 0; s < 4; ++s) {
            acc = __builtin_amdgcn_mfma_f32_32x32x16_bf16(ah[s], bh[s], acc, 0, 0, 0);
            acc = __builtin_amdgcn_mfma_f32_32x32x16_bf16(ah[s], bl[s], acc, 0, 0, 0);
            acc = __builtin_amdgcn_mfma_f32_32x32x16_bf16(al[s], bh[s], acc, 0, 0, 0);
        }
        const unsigned kg = (unsigned)(cbk * 128 + c * 32 + lm);   // 14-bit code id
        #pragma unroll
        for (int r = 0; r < 16; ++r) {
            const float dist = -acc[r];
            unsigned q = (unsigned)(int)fmaf(dist, 65536.0f, 131072.0f);
            q = q > 262143u ? 262143u : q;
            unsigned key = (q << 14) | kg;
            key = ((mv[r] >> lm) & 1u) ? key : 0xFFFFFFFFu;        // dropped code
            const unsigned mx = k1[r] > key ? k1[r] : key;
            k1[r] = k1[r] < key ? k1[r] : key;
            k2[r] = k2[r] < mx ? k2[r] : mx;
        }
    }

    // reduce over the 32 codes held by this half-wave
    #pragma unroll
    for (int r = 0; r < 16; ++r) {
        unsigned a = k1[r], b = k2[r];
        #pragma unroll
        for (int off = 1; off < 32; off <<= 1) {
            const unsigned oa = (unsigned)__shfl_xor((int)a, off, 32);
            const unsigned ob = (unsigned)__shfl_xor((int)b, off, 32);
            const unsigned mx = a > oa ? a : oa;
            a = a < oa ? a : oa;
            const unsigned mn = b < ob ? b : ob;
            b = mn < mx ? mn : mx;
        }
        k1[r] = a; k2[r] = b;
    }
    if (lm == 0) {
        #pragma unroll
        for (int r = 0; r < 16; ++r) {
            const int row = row0 + (r & 3) + 8 * (r >> 2) + 4 * lh;
            pk1[(size_t)row * ncb + cbk] = k1[r];
            pk2[(size_t)row * ncb + cbk] = k2[r];
        }
    }
}

// ---------------------------------------------------------------------------
// combine 128 block-partials per row; flag rows with top-2 gap < 10 quanta
// ---------------------------------------------------------------------------
__global__ __launch_bounds__(256) void k_reduce2(const unsigned* __restrict__ pk1,
                                                 const unsigned* __restrict__ pk2,
                                                 int* __restrict__ bestidx,
                                                 int* __restrict__ fixlist,
                                                 int* __restrict__ fixcnt,
                                                 int ncb) {
    const int t = threadIdx.x;
    const int wv = t >> 6, lane = t & 63;
    const int row = blockIdx.x * 4 + wv;
    const unsigned* p1 = pk1 + (size_t)row * ncb;
    const unsigned* p2 = pk2 + (size_t)row * ncb;
    const unsigned a1 = p1[lane],      a2 = p2[lane];
    const unsigned b1 = p1[lane + 64], b2 = p2[lane + 64];
    unsigned mx = a1 > b1 ? a1 : b1;
    unsigned k1 = a1 < b1 ? a1 : b1;
    unsigned k2 = a2 < b2 ? a2 : b2;
    k2 = k2 < mx ? k2 : mx;
    #pragma unroll
    for (int off = 1; off < 64; off <<= 1) {
        const unsigned oa = (unsigned)__shfl_xor((int)k1, off, 64);
        const unsigned ob = (unsigned)__shfl_xor((int)k2, off, 64);
        mx = k1 > oa ? k1 : oa;
        k1 = k1 < oa ? k1 : oa;
        const unsigned mn = k2 < ob ? k2 : ob;
        k2 = mn < mx ? mn : mx;
    }
    if (lane == 0) {
        bestidx[row] = (int)(k1 & 16383u);
        if ((k2 >> 14) - (k1 >> 14) < 10u) {
            const int p = atomicAdd(fixcnt, 1);
            fixlist[p] = row;
        }
    }
}

// ---------------------------------------------------------------------------
// gather + write all outputs
// ---------------------------------------------------------------------------
__global__ __launch_bounds__(256) void k_out(const float* __restrict__ xn,
                                             const float* __restrict__ cb,
                                             const int* __restrict__ bestidx,
                                             float* __restrict__ out, int B) {
    const int t = threadIdx.x;
    const int wv = t >> 6, lane = t & 63;
    const int row = blockIdx.x * 4 + wv;
    const int bi = bestidx[row];
    const float zv  = cb[(size_t)bi * D + lane];
    const float xnv = xn[(size_t)row * D + lane];
    out[(size_t)row * D + lane] = xnv + (zv - xnv);                 // z_q
    out[(size_t)B * D + (size_t)row * D + lane] = zv;               // z
    if (lane == 0) out[(size_t)3 * B * D + row] = (float)bi;        // index
}

// ---------------------------------------------------------------------------
// exact fp32 rescan for flagged (near-tie) rows; overwrites their outputs
// ---------------------------------------------------------------------------
__global__ __launch_bounds__(256) void k_fix(const float* __restrict__ xn,
                                             const float* __restrict__ cb,
                                             const int* __restrict__ mask,
                                             const int* __restrict__ training,
                                             const int* __restrict__ fixlist,
                                             const int* __restrict__ fixcnt,
                                             float* __restrict__ out, int B, int K) {
    const int nf = *fixcnt;
    const int tr = training[0];
    __shared__ float sv[256];
    __shared__ int   si[256];
    const int t = threadIdx.x;
    for (int i = blockIdx.x; i < nf; i += gridDim.x) {
        const int row = fixlist[i];
        const float* xr = xn + (size_t)row * D;
        float b1 = FLT_MAX; int i1 = 0;
        for (int k = t; k < K; k += 256) {
            const float* cr = cb + (size_t)k * D;
            float s = 0.f;
            #pragma unroll
            for (int d = 0; d < D; ++d) s = fmaf(xr[d], cr[d], s);
            const int m = mask[(size_t)row * K + k];
            const float dist = (tr && m == 0) ? 1000000000.0f : -s;
            if (dist < b1) { b1 = dist; i1 = k; }
        }
        sv[t] = b1; si[t] = i1;
        __syncthreads();
        for (int s = 128; s; s >>= 1) {
            if (t < s) {
                const float ov = sv[t + s]; const int oi = si[t + s];
                if (ov < sv[t] || (ov == sv[t] && oi < si[t])) { sv[t] = ov; si[t] = oi; }
            }
            __syncthreads();
        }
        const int bi = si[0];
        if (t < 64) {
            const float zv  = cb[(size_t)bi * D + t];
            const float xnv = xr[t];
            out[(size_t)row * D + t] = xnv + (zv - xnv);
            out[(size_t)B * D + (size_t)row * D + t] = zv;
        }
        if (t == 0) out[(size_t)3 * B * D + row] = (float)bi;
        __syncthreads();
    }
}

extern "C" void kernel_launch(void* const* d_in, const int* in_sizes, int n_in,
                              void* d_out, int out_size, void* d_ws, size_t ws_size,
                              hipStream_t stream) {
    const float* x    = (const float*)d_in[0];
    const float* cbin = (const float*)d_in[1];
    const int* mask   = (const int*)d_in[2];
    const int* train  = (const int*)d_in[3];
    const int B = in_sizes[0] / D;   // 16384
    const int K = in_sizes[1] / D;   // 16384
    const int ncb = K / 128;         // 128 code-blocks
    float* out = (float*)d_out;
    float* out_xn = out + (size_t)2 * B * D;

    char* w = (char*)d_ws;
    float* cbw          = (float*)w;                               // 4 MB
    unsigned short* xhw = (unsigned short*)(w + (size_t)K * D * 4);
    unsigned short* xlw = xhw + (size_t)B * D;
    unsigned short* chw = xlw + (size_t)B * D;
    unsigned short* clw = chw + (size_t)K * D;
    unsigned* pk1       = (unsigned*)(clw + (size_t)K * D);        // 8 MB
    unsigned* pk2       = pk1 + (size_t)B * ncb;                   // 8 MB
    int* bestidx        = (int*)(pk2 + (size_t)B * ncb);
    int* fixlist        = bestidx + B;
    int* fixcnt         = fixlist + B;
    unsigned* bits      = (unsigned*)(fixcnt + 64);                // 32 MB

    hipMemsetAsync(fixcnt, 0, sizeof(int), stream);

    const long long nseg = (long long)B * K / 64;
    k_bitpack<<<2048, 256, 0, stream>>>(mask, train, bits, nseg);
    k_prep_cb<<<K / 4, 256, 0, stream>>>(cbin, cbw, chw, clw);
    k_prep_x <<<B / 4, 256, 0, stream>>>(x, out_xn, xhw, xlw);
    k_mfma   <<<(B / 128) * ncb, 256, 0, stream>>>(xhw, xlw, chw, clw, bits,
                                                   pk1, pk2, K, ncb);
    k_reduce2<<<B / 4, 256, 0, stream>>>(pk1, pk2, bestidx, fixlist, fixcnt, ncb);
    k_out    <<<B / 4, 256, 0, stream>>>(out_xn, cbw, bestidx, out, B);
    k_fix    <<<256, 256, 0, stream>>>(out_xn, cbw, mask, train, fixlist, fixcnt,
                                       out, B, K);
}

// Round 7
// 539.433 us; speedup vs baseline: 1.3245x; 1.3245x over previous
//
#include <hip/hip_runtime.h>
#include <math.h>
#include <float.h>

#define EPSV 1e-8f
constexpr int D = 64;

typedef __attribute__((ext_vector_type(8)))  short short8;
typedef __attribute__((ext_vector_type(16))) float f32x16;

static __device__ __forceinline__ unsigned short f2bf(float f) {
    unsigned u = __float_as_uint(f);
    unsigned r = u + 0x7FFFu + ((u >> 16) & 1u);   // round-to-nearest-even
    return (unsigned short)(r >> 16);
}
static __device__ __forceinline__ float bf2f(unsigned short b) {
    return __uint_as_float(((unsigned)b) << 16);
}
static __device__ __forceinline__ unsigned umin2(unsigned a, unsigned b) { return a < b ? a : b; }
static __device__ __forceinline__ unsigned umax2(unsigned a, unsigned b) { return a > b ? a : b; }

// fragment-ready layout: entity panel p=e>>5, k-slot q=k>>3:
//   u16 index = p*2048 + q*256 + (e&31)*8 + (k&7)
// lane l's 8-bf16 MFMA fragment (entity=l&31, k=(l>>5)*8+j+16s) is one 16B load.
static __device__ __forceinline__ size_t fragidx(int e, int k) {
    return (size_t)(e >> 5) * 2048 + (size_t)(k >> 3) * 256 + (e & 31) * 8 + (k & 7);
}

// ---------------------------------------------------------------------------
// prep: normalize codebook. cb fp32 (for gather) + double-normalized hi/lo
// bf16 fragments.
// ---------------------------------------------------------------------------
__global__ __launch_bounds__(256) void k_prep_cb(const float* __restrict__ cbin,
                                                 float* __restrict__ cb,
                                                 unsigned short* __restrict__ ch,
                                                 unsigned short* __restrict__ cl) {
    const int t = threadIdx.x;
    const int wv = t >> 6, lane = t & 63;
    const int code = blockIdx.x * 4 + wv;
    float v = cbin[(size_t)code * D + lane];
    float ss = v * v;
    #pragma unroll
    for (int off = 32; off; off >>= 1) ss += __shfl_xor(ss, off, 64);
    const float c1 = v / (sqrtf(ss) + EPSV);
    cb[(size_t)code * D + lane] = c1;
    float ss2 = c1 * c1;
    #pragma unroll
    for (int off = 32; off; off >>= 1) ss2 += __shfl_xor(ss2, off, 64);
    const float c2 = c1 / (sqrtf(ss2) + EPSV);
    const unsigned short h = f2bf(c2);
    const size_t fi = fragidx(code, lane);
    ch[fi] = h;
    cl[fi] = f2bf(c2 - bf2f(h));
}

// ---------------------------------------------------------------------------
// prep: normalize x -> xn (fp32, straight to d_out region 2) + hi/lo fragments
// ---------------------------------------------------------------------------
__global__ __launch_bounds__(256) void k_prep_x(const float* __restrict__ xin,
                                                float* __restrict__ xn,
                                                unsigned short* __restrict__ xh,
                                                unsigned short* __restrict__ xl) {
    const int t = threadIdx.x;
    const int wv = t >> 6, lane = t & 63;
    const int row = blockIdx.x * 4 + wv;
    float v = xin[(size_t)row * D + lane];
    float ss = v * v;
    #pragma unroll
    for (int off = 32; off; off >>= 1) ss += __shfl_xor(ss, off, 64);
    const float xv = v / (sqrtf(ss) + EPSV);
    xn[(size_t)row * D + lane] = xv;
    const unsigned short h = f2bf(xv);
    const size_t fi = fragidx(row, lane);
    xh[fi] = h;
    xl[fi] = f2bf(xv - bf2f(h));
}

// ---------------------------------------------------------------------------
// main: 128 rows x 128 codes per block, 4 waves. SWAPPED operands:
//   A = code fragments, B = x-row fragments  ->  D[code][xrow], col=lane&31=xrow.
// Each lane owns ONE x-row; its 16 accum regs span 16 codes -> argmin is
// per-lane register u32-min (key=(q<<14)|code), 2 shuffles per block total.
// Mask: one dwordx4 per reg-quad, consumed straight from HBM (one full pass).
// ---------------------------------------------------------------------------
__global__ __launch_bounds__(256, 4) void k_mfma(const unsigned short* __restrict__ xh,
                                                 const unsigned short* __restrict__ xl,
                                                 const unsigned short* __restrict__ ch,
                                                 const unsigned short* __restrict__ cl,
                                                 const int* __restrict__ mask,
                                                 const int* __restrict__ training,
                                                 unsigned* __restrict__ pk1,
                                                 unsigned* __restrict__ pk2,
                                                 int B, int K, int ncb) {
    const int t = threadIdx.x;
    const int wv = t >> 6, lane = t & 63;
    const int lh = lane >> 5, lm = lane & 31;
    const int cbk = blockIdx.x % ncb;
    const int rb  = blockIdx.x / ncb;
    const int tr = training[0];

    const short8* xh8 = (const short8*)xh;
    const short8* xl8 = (const short8*)xl;
    const short8* ch8 = (const short8*)ch;
    const short8* cl8 = (const short8*)cl;

    const int rp = rb * 4 + wv;                  // this wave's 32-row panel
    const int row = rp * 32 + lm;                // this lane's x-row

    // B fragments (x rows), held for the whole block
    short8 bh[4], bl[4];
    #pragma unroll
    for (int s = 0; s < 4; ++s) {
        const size_t bi = (size_t)rp * 256 + (s * 2 + lh) * 32 + lm;
        bh[s] = xh8[bi];
        bl[s] = xl8[bi];
    }

    const int* mrow = mask + (size_t)row * K + cbk * 128 + 4 * lh;

    unsigned k1 = 0xFFFFFFFFu, k2 = 0xFFFFFFFFu;

    #pragma unroll
    for (int c = 0; c < 4; ++c) {
        const int cp = cbk * 4 + c;              // code panel of 32
        short8 ah[4], al[4];
        #pragma unroll
        for (int s = 0; s < 4; ++s) {
            const size_t ai = (size_t)cp * 256 + (s * 2 + lh) * 32 + lm;
            ah[s] = ch8[ai];
            al[s] = cl8[ai];
        }
        int4 mq[4];                              // mask for codes {0-3,8-11,16-19,24-27}+4lh
        #pragma unroll
        for (int g2 = 0; g2 < 4; ++g2)
            mq[g2] = *(const int4*)(mrow + c * 32 + g2 * 8);

        f32x16 acc;
        #pragma unroll
        for (int i = 0; i < 16; ++i) acc[i] = 0.f;
        #pragma unroll
        for (int s = 0; s < 4; ++s) {
            acc = __builtin_amdgcn_mfma_f32_32x32x16_bf16(ah[s], bh[s], acc, 0, 0, 0);
            acc = __builtin_amdgcn_mfma_f32_32x32x16_bf16(ah[s], bl[s], acc, 0, 0, 0);
            acc = __builtin_amdgcn_mfma_f32_32x32x16_bf16(al[s], bh[s], acc, 0, 0, 0);
        }
        #pragma unroll
        for (int r = 0; r < 16; ++r) {
            const int clocal = (r & 3) + 8 * (r >> 2) + 4 * lh;     // code in panel
            const unsigned kg = (unsigned)(cbk * 128 + c * 32 + clocal);
            const float dist = -acc[r];
            unsigned q = (unsigned)(int)fmaf(dist, 65536.0f, 131072.0f);
            q = q > 262143u ? 262143u : q;
            unsigned key = (q << 14) | kg;
            const int m = (r & 3) == 0 ? mq[r >> 2].x :
                          (r & 3) == 1 ? mq[r >> 2].y :
                          (r & 3) == 2 ? mq[r >> 2].z : mq[r >> 2].w;
            key = (m != 0 || tr == 0) ? key : 0xFFFFFFFFu;          // dropped code
            k2 = umin2(k2, umax2(k1, key));
            k1 = umin2(k1, key);
        }
    }

    // merge the two half-lanes holding the same x-row (codes split across halves)
    const unsigned o1 = (unsigned)__shfl_xor((int)k1, 32, 64);
    const unsigned o2 = (unsigned)__shfl_xor((int)k2, 32, 64);
    const unsigned mx = umax2(k1, o1);
    k1 = umin2(k1, o1);
    k2 = umin2(umin2(k2, o2), mx);

    if (lh == 0) {                               // coalesced 32-dword writes
        pk1[(size_t)cbk * B + row] = k1;
        pk2[(size_t)cbk * B + row] = k2;
    }
}

// ---------------------------------------------------------------------------
// combine ncb block-partials per row (coalesced row-major loads);
// flag rows with top-2 gap < 10 quanta for exact rescan
// ---------------------------------------------------------------------------
__global__ __launch_bounds__(256) void k_reduce2(const unsigned* __restrict__ pk1,
                                                 const unsigned* __restrict__ pk2,
                                                 int* __restrict__ bestidx,
                                                 int* __restrict__ fixlist,
                                                 int* __restrict__ fixcnt,
                                                 int B, int ncb) {
    const int t = threadIdx.x;
    const int row = blockIdx.x * 256 + t;
    unsigned k1 = 0xFFFFFFFFu, k2 = 0xFFFFFFFFu;
    for (int c = 0; c < ncb; ++c) {
        const unsigned a1 = pk1[(size_t)c * B + row];
        const unsigned a2 = pk2[(size_t)c * B + row];
        k2 = umin2(umin2(k2, a2), umax2(k1, a1));
        k1 = umin2(k1, a1);
    }
    bestidx[row] = (int)(k1 & 16383u);
    if ((k2 >> 14) - (k1 >> 14) < 10u) {
        const int p = atomicAdd(fixcnt, 1);
        fixlist[p] = row;
    }
}

// ---------------------------------------------------------------------------
// gather + write all outputs
// ---------------------------------------------------------------------------
__global__ __launch_bounds__(256) void k_out(const float* __restrict__ xn,
                                             const float* __restrict__ cb,
                                             const int* __restrict__ bestidx,
                                             float* __restrict__ out, int B) {
    const int t = threadIdx.x;
    const int wv = t >> 6, lane = t & 63;
    const int row = blockIdx.x * 4 + wv;
    const int bi = bestidx[row];
    const float zv  = cb[(size_t)bi * D + lane];
    const float xnv = xn[(size_t)row * D + lane];
    out[(size_t)row * D + lane] = xnv + (zv - xnv);                 // z_q
    out[(size_t)B * D + (size_t)row * D + lane] = zv;               // z
    if (lane == 0) out[(size_t)3 * B * D + row] = (float)bi;        // index
}

// ---------------------------------------------------------------------------
// exact fp32 rescan for flagged (near-tie) rows; overwrites their outputs
// ---------------------------------------------------------------------------
__global__ __launch_bounds__(256) void k_fix(const float* __restrict__ xn,
                                             const float* __restrict__ cb,
                                             const int* __restrict__ mask,
                                             const int* __restrict__ training,
                                             const int* __restrict__ fixlist,
                                             const int* __restrict__ fixcnt,
                                             float* __restrict__ out, int B, int K) {
    const int nf = *fixcnt;
    const int tr = training[0];
    __shared__ float sv[256];
    __shared__ int   si[256];
    const int t = threadIdx.x;
    for (int i = blockIdx.x; i < nf; i += gridDim.x) {
        const int row = fixlist[i];
        const float* xr = xn + (size_t)row * D;
        float b1 = FLT_MAX; int i1 = 0;
        for (int k = t; k < K; k += 256) {
            const float* cr = cb + (size_t)k * D;
            float s = 0.f;
            #pragma unroll
            for (int d = 0; d < D; ++d) s = fmaf(xr[d], cr[d], s);
            const int m = mask[(size_t)row * K + k];
            const float dist = (tr && m == 0) ? 1000000000.0f : -s;
            if (dist < b1) { b1 = dist; i1 = k; }
        }
        sv[t] = b1; si[t] = i1;
        __syncthreads();
        for (int s = 128; s; s >>= 1) {
            if (t < s) {
                const float ov = sv[t + s]; const int oi = si[t + s];
                if (ov < sv[t] || (ov == sv[t] && oi < si[t])) { sv[t] = ov; si[t] = oi; }
            }
            __syncthreads();
        }
        const int bi = si[0];
        if (t < 64) {
            const float zv  = cb[(size_t)bi * D + t];
            const float xnv = xr[t];
            out[(size_t)row * D + t] = xnv + (zv - xnv);
            out[(size_t)B * D + (size_t)row * D + t] = zv;
        }
        if (t == 0) out[(size_t)3 * B * D + row] = (float)bi;
        __syncthreads();
    }
}

extern "C" void kernel_launch(void* const* d_in, const int* in_sizes, int n_in,
                              void* d_out, int out_size, void* d_ws, size_t ws_size,
                              hipStream_t stream) {
    const float* x    = (const float*)d_in[0];
    const float* cbin = (const float*)d_in[1];
    const int* mask   = (const int*)d_in[2];
    const int* train  = (const int*)d_in[3];
    const int B = in_sizes[0] / D;   // 16384
    const int K = in_sizes[1] / D;   // 16384
    const int ncb = K / 128;         // 128 code-blocks
    float* out = (float*)d_out;
    float* out_xn = out + (size_t)2 * B * D;

    char* w = (char*)d_ws;
    float* cbw          = (float*)w;                               // 4 MB
    unsigned short* xhw = (unsigned short*)(w + (size_t)K * D * 4);
    unsigned short* xlw = xhw + (size_t)B * D;
    unsigned short* chw = xlw + (size_t)B * D;
    unsigned short* clw = chw + (size_t)K * D;
    unsigned* pk1       = (unsigned*)(clw + (size_t)K * D);        // 8 MB
    unsigned* pk2       = pk1 + (size_t)B * ncb;                   // 8 MB
    int* bestidx        = (int*)(pk2 + (size_t)B * ncb);
    int* fixlist        = bestidx + B;
    int* fixcnt         = fixlist + B;

    hipMemsetAsync(fixcnt, 0, sizeof(int), stream);

    k_prep_cb<<<K / 4, 256, 0, stream>>>(cbin, cbw, chw, clw);
    k_prep_x <<<B / 4, 256, 0, stream>>>(x, out_xn, xhw, xlw);
    k_mfma   <<<(B / 128) * ncb, 256, 0, stream>>>(xhw, xlw, chw, clw, mask, train,
                                                   pk1, pk2, B, K, ncb);
    k_reduce2<<<B / 256, 256, 0, stream>>>(pk1, pk2, bestidx, fixlist, fixcnt, B, ncb);
    k_out    <<<B / 4, 256, 0, stream>>>(out_xn, cbw, bestidx, out, B);
    k_fix    <<<256, 256, 0, stream>>>(out_xn, cbw, mask, train, fixlist, fixcnt,
                                       out, B, K);
}

// Round 9
// 501.118 us; speedup vs baseline: 1.4258x; 1.0765x over previous
//
#include <hip/hip_runtime.h>
#include <math.h>
#include <float.h>

#define EPSV 1e-8f
constexpr int D = 64;

typedef __attribute__((ext_vector_type(8)))  short short8;
typedef __attribute__((ext_vector_type(16))) float f32x16;

static __device__ __forceinline__ unsigned short f2bf(float f) {
    unsigned u = __float_as_uint(f);
    unsigned r = u + 0x7FFFu + ((u >> 16) & 1u);   // round-to-nearest-even
    return (unsigned short)(r >> 16);
}
static __device__ __forceinline__ float bf2f(unsigned short b) {
    return __uint_as_float(((unsigned)b) << 16);
}
static __device__ __forceinline__ unsigned umin2(unsigned a, unsigned b) { return a < b ? a : b; }
static __device__ __forceinline__ unsigned umax2(unsigned a, unsigned b) { return a > b ? a : b; }

// fragment-ready layout: entity panel p=e>>5, k-slot q=k>>3:
//   u16 index = p*2048 + q*256 + (e&31)*8 + (k&7)
static __device__ __forceinline__ size_t fragidx(int e, int k) {
    return (size_t)(e >> 5) * 2048 + (size_t)(k >> 3) * 256 + (e & 31) * 8 + (k & 7);
}

// ---------------------------------------------------------------------------
// prep: normalize codebook. cb fp32 (for gather) + double-normalized hi/lo
// bf16 fragments.
// ---------------------------------------------------------------------------
__global__ __launch_bounds__(256) void k_prep_cb(const float* __restrict__ cbin,
                                                 float* __restrict__ cb,
                                                 unsigned short* __restrict__ ch,
                                                 unsigned short* __restrict__ cl) {
    const int t = threadIdx.x;
    const int wv = t >> 6, lane = t & 63;
    const int code = blockIdx.x * 4 + wv;
    float v = cbin[(size_t)code * D + lane];
    float ss = v * v;
    #pragma unroll
    for (int off = 32; off; off >>= 1) ss += __shfl_xor(ss, off, 64);
    const float c1 = v / (sqrtf(ss) + EPSV);
    cb[(size_t)code * D + lane] = c1;
    float ss2 = c1 * c1;
    #pragma unroll
    for (int off = 32; off; off >>= 1) ss2 += __shfl_xor(ss2, off, 64);
    const float c2 = c1 / (sqrtf(ss2) + EPSV);
    const unsigned short h = f2bf(c2);
    const size_t fi = fragidx(code, lane);
    ch[fi] = h;
    cl[fi] = f2bf(c2 - bf2f(h));
}

// ---------------------------------------------------------------------------
// prep: normalize x -> xn (fp32, straight to d_out region 2) + hi/lo fragments
// also zeroes fixcnt (stream-ordered before k_reduce2)
// ---------------------------------------------------------------------------
__global__ __launch_bounds__(256) void k_prep_x(const float* __restrict__ xin,
                                                float* __restrict__ xn,
                                                unsigned short* __restrict__ xh,
                                                unsigned short* __restrict__ xl,
                                                int* __restrict__ fixcnt) {
    const int t = threadIdx.x;
    if (blockIdx.x == 0 && t == 0) *fixcnt = 0;
    const int wv = t >> 6, lane = t & 63;
    const int row = blockIdx.x * 4 + wv;
    float v = xin[(size_t)row * D + lane];
    float ss = v * v;
    #pragma unroll
    for (int off = 32; off; off >>= 1) ss += __shfl_xor(ss, off, 64);
    const float xv = v / (sqrtf(ss) + EPSV);
    xn[(size_t)row * D + lane] = xv;
    const unsigned short h = f2bf(xv);
    const size_t fi = fragidx(row, lane);
    xh[fi] = h;
    xl[fi] = f2bf(xv - bf2f(h));
}

// ---------------------------------------------------------------------------
// main: 128 rows x 128 codes per block, 4 waves. Swapped operands:
//   A = code fragments, B = x-row fragments -> acc col (lane&31) = x-row.
// Mask: read COALESCED (lanes<->codes), transposed in-register via
// __ballot + per-lane select, so each lane holds its own row's 128 bits.
// Argmin: per-lane register u32-min of key=(q<<14)|code; 2 shuffles/block.
// ---------------------------------------------------------------------------
__global__ __launch_bounds__(256, 4) void k_mfma(const unsigned short* __restrict__ xh,
                                                 const unsigned short* __restrict__ xl,
                                                 const unsigned short* __restrict__ ch,
                                                 const unsigned short* __restrict__ cl,
                                                 const int* __restrict__ mask,
                                                 const int* __restrict__ training,
                                                 unsigned* __restrict__ pk1,
                                                 unsigned* __restrict__ pk2,
                                                 int B, int K, int ncb) {
    const int t = threadIdx.x;
    const int wv = t >> 6, lane = t & 63;
    const int lh = lane >> 5, lm = lane & 31;
    const int cbk = blockIdx.x % ncb;
    const int rb  = blockIdx.x / ncb;
    const int tr = training[0];

    const short8* xh8 = (const short8*)xh;
    const short8* xl8 = (const short8*)xl;
    const short8* ch8 = (const short8*)ch;
    const short8* cl8 = (const short8*)cl;

    const int rp = rb * 4 + wv;                  // this wave's 32-row panel
    const int row = rp * 32 + lm;                // this lane's x-row

    // B fragments (x rows), held for the whole block
    short8 bh[4], bl[4];
    #pragma unroll
    for (int s = 0; s < 4; ++s) {
        const size_t bi = (size_t)rp * 256 + (s * 2 + lh) * 32 + lm;
        bh[s] = xh8[bi];
        bl[s] = xl8[bi];
    }

    // ---- mask transpose: coalesced row reads -> ballot -> per-lane select ----
    // after this, lane L holds the 128 mask bits of row rp*32+(L&31) in vb0..3
    unsigned vb0 = 0, vb1 = 0, vb2 = 0, vb3 = 0;
    {
        const int* mrow0 = mask + (size_t)(rp * 32) * K + cbk * 128;
        #pragma unroll
        for (int r = 0; r < 32; ++r) {
            const int v0 = mrow0[(size_t)r * K + lane];
            const int v1 = mrow0[(size_t)r * K + 64 + lane];
            const unsigned long long b01 = __ballot(v0 != 0 || tr == 0);
            const unsigned long long b23 = __ballot(v1 != 0 || tr == 0);
            const bool sel = (lm == r);          // true in BOTH half-waves
            vb0 = sel ? (unsigned)b01 : vb0;
            vb1 = sel ? (unsigned)(b01 >> 32) : vb1;
            vb2 = sel ? (unsigned)b23 : vb2;
            vb3 = sel ? (unsigned)(b23 >> 32) : vb3;
        }
    }
    const int lh4 = lh * 4;
    // pre-shift by 4*lh and invert: bit 'base' of vbn[c] == NOT mask(code kbase+base)
    const unsigned vbn[4] = { ~(vb0 >> lh4), ~(vb1 >> lh4), ~(vb2 >> lh4), ~(vb3 >> lh4) };

    unsigned k1 = 0xFFFFFFFFu, k2 = 0xFFFFFFFFu;

    #pragma unroll
    for (int c = 0; c < 4; ++c) {
        const int cp = cbk * 4 + c;              // code panel of 32
        short8 ah[4], al[4];
        #pragma unroll
        for (int s = 0; s < 4; ++s) {
            const size_t ai = (size_t)cp * 256 + (s * 2 + lh) * 32 + lm;
            ah[s] = ch8[ai];
            al[s] = cl8[ai];
        }
        f32x16 acc;
        #pragma unroll
        for (int i = 0; i < 16; ++i) acc[i] = 0.f;
        #pragma unroll
        for (int s = 0; s < 4; ++s) {
            acc = __builtin_amdgcn_mfma_f32_32x32x16_bf16(ah[s], bh[s], acc, 0, 0, 0);
            acc = __builtin_amdgcn_mfma_f32_32x32x16_bf16(ah[s], bl[s], acc, 0, 0, 0);
            acc = __builtin_amdgcn_mfma_f32_32x32x16_bf16(al[s], bh[s], acc, 0, 0, 0);
        }
        const unsigned kbase = (unsigned)(cbk * 128 + c * 32 + lh4);
        const unsigned vbnc = vbn[c];
        #pragma unroll
        for (int r = 0; r < 16; ++r) {
            const int base = (r & 3) + 8 * (r >> 2);               // compile-time
            const float qf = fmaf(acc[r], -65536.0f, 131072.0f);   // dist*2^16+2^17
            int qi = (int)qf;
            qi = qi < 0 ? 0 : (qi > 262143 ? 262143 : qi);
            unsigned key = ((unsigned)qi << 14) | kbase | (unsigned)base;
            key |= (unsigned)((int)(vbnc << (31 - base)) >> 31);   // dropped -> ~0
            k2 = umin2(k2, umax2(k1, key));
            k1 = umin2(k1, key);
        }
    }

    // merge the two half-lanes holding the same x-row
    const unsigned o1 = (unsigned)__shfl_xor((int)k1, 32, 64);
    const unsigned o2 = (unsigned)__shfl_xor((int)k2, 32, 64);
    const unsigned mx = umax2(k1, o1);
    k1 = umin2(k1, o1);
    k2 = umin2(umin2(k2, o2), mx);

    if (lh == 0) {                               // coalesced 32-dword writes
        pk1[(size_t)cbk * B + row] = k1;
        pk2[(size_t)cbk * B + row] = k2;
    }
}

// ---------------------------------------------------------------------------
// combine ncb block-partials per row (4-way split over c + LDS merge);
// flag rows with top-2 gap < 10 quanta for exact rescan
// ---------------------------------------------------------------------------
__global__ __launch_bounds__(256) void k_reduce2(const unsigned* __restrict__ pk1,
                                                 const unsigned* __restrict__ pk2,
                                                 int* __restrict__ bestidx,
                                                 int* __restrict__ fixlist,
                                                 int* __restrict__ fixcnt,
                                                 int B, int ncb) {
    __shared__ unsigned s1[4][64], s2[4][64];
    const int t = threadIdx.x;
    const int sub = t >> 6, rl = t & 63;
    const int row = blockIdx.x * 64 + rl;
    const int cpq = ncb / 4;
    unsigned k1 = 0xFFFFFFFFu, k2 = 0xFFFFFFFFu;
    for (int c = sub * cpq; c < (sub + 1) * cpq; ++c) {
        const unsigned a1 = pk1[(size_t)c * B + row];
        const unsigned a2 = pk2[(size_t)c * B + row];
        k2 = umin2(umin2(k2, a2), umax2(k1, a1));
        k1 = umin2(k1, a1);
    }
    s1[sub][rl] = k1; s2[sub][rl] = k2;
    __syncthreads();
    if (sub == 0) {
        #pragma unroll
        for (int j = 1; j < 4; ++j) {
            const unsigned a1 = s1[j][rl], a2 = s2[j][rl];
            k2 = umin2(umin2(k2, a2), umax2(k1, a1));
            k1 = umin2(k1, a1);
        }
        bestidx[row] = (int)(k1 & 16383u);
        if ((k2 >> 14) - (k1 >> 14) < 10u) {
            const int p = atomicAdd(fixcnt, 1);
            fixlist[p] = row;
        }
    }
}

// ---------------------------------------------------------------------------
// gather + write all outputs
// ---------------------------------------------------------------------------
__global__ __launch_bounds__(256) void k_out(const float* __restrict__ xn,
                                             const float* __restrict__ cb,
                                             const int* __restrict__ bestidx,
                                             float* __restrict__ out, int B) {
    const int t = threadIdx.x;
    const int wv = t >> 6, lane = t & 63;
    const int row = blockIdx.x * 4 + wv;
    const int bi = bestidx[row];
    const float zv  = cb[(size_t)bi * D + lane];
    const float xnv = xn[(size_t)row * D + lane];
    out[(size_t)row * D + lane] = xnv + (zv - xnv);                 // z_q
    out[(size_t)B * D + (size_t)row * D + lane] = zv;               // z
    if (lane == 0) out[(size_t)3 * B * D + row] = (float)bi;        // index
}

// ---------------------------------------------------------------------------
// exact fp32 rescan for flagged (near-tie) rows; overwrites their outputs
// ---------------------------------------------------------------------------
__global__ __launch_bounds__(256) void k_fix(const float* __restrict__ xn,
                                             const float* __restrict__ cb,
                                             const int* __restrict__ mask,
                                             const int* __restrict__ training,
                                             const int* __restrict__ fixlist,
                                             const int* __restrict__ fixcnt,
                                             float* __restrict__ out, int B, int K) {
    const int nf = *fixcnt;
    const int tr = training[0];
    __shared__ float sv[256];
    __shared__ int   si[256];
    const int t = threadIdx.x;
    for (int i = blockIdx.x; i < nf; i += gridDim.x) {
        const int row = fixlist[i];
        const float* xr = xn + (size_t)row * D;
        float b1 = FLT_MAX; int i1 = 0;
        for (int k = t; k < K; k += 256) {
            const float* cr = cb + (size_t)k * D;
            float s = 0.f;
            #pragma unroll
            for (int d = 0; d < D; ++d) s = fmaf(xr[d], cr[d], s);
            const int m = mask[(size_t)row * K + k];
            const float dist = (tr && m == 0) ? 1000000000.0f : -s;
            if (dist < b1) { b1 = dist; i1 = k; }
        }
        sv[t] = b1; si[t] = i1;
        __syncthreads();
        for (int s = 128; s; s >>= 1) {
            if (t < s) {
                const float ov = sv[t + s]; const int oi = si[t + s];
                if (ov < sv[t] || (ov == sv[t] && oi < si[t])) { sv[t] = ov; si[t] = oi; }
            }
            __syncthreads();
        }
        const int bi = si[0];
        if (t < 64) {
            const float zv  = cb[(size_t)bi * D + t];
            const float xnv = xr[t];
            out[(size_t)row * D + t] = xnv + (zv - xnv);
            out[(size_t)B * D + (size_t)row * D + t] = zv;
        }
        if (t == 0) out[(size_t)3 * B * D + row] = (float)bi;
        __syncthreads();
    }
}

extern "C" void kernel_launch(void* const* d_in, const int* in_sizes, int n_in,
                              void* d_out, int out_size, void* d_ws, size_t ws_size,
                              hipStream_t stream) {
    const float* x    = (const float*)d_in[0];
    const float* cbin = (const float*)d_in[1];
    const int* mask   = (const int*)d_in[2];
    const int* train  = (const int*)d_in[3];
    const int B = in_sizes[0] / D;   // 16384
    const int K = in_sizes[1] / D;   // 16384
    const int ncb = K / 128;         // 128 code-blocks
    float* out = (float*)d_out;
    float* out_xn = out + (size_t)2 * B * D;

    char* w = (char*)d_ws;
    float* cbw          = (float*)w;                               // 4 MB
    unsigned short* xhw = (unsigned short*)(w + (size_t)K * D * 4);
    unsigned short* xlw = xhw + (size_t)B * D;
    unsigned short* chw = xlw + (size_t)B * D;
    unsigned short* clw = chw + (size_t)K * D;
    unsigned* pk1       = (unsigned*)(clw + (size_t)K * D);        // 8 MB
    unsigned* pk2       = pk1 + (size_t)B * ncb;                   // 8 MB
    int* bestidx        = (int*)(pk2 + (size_t)B * ncb);
    int* fixlist        = bestidx + B;
    int* fixcnt         = fixlist + B;

    k_prep_cb<<<K / 4, 256, 0, stream>>>(cbin, cbw, chw, clw);
    k_prep_x <<<B / 4, 256, 0, stream>>>(x, out_xn, xhw, xlw, fixcnt);
    k_mfma   <<<(B / 128) * ncb, 256, 0, stream>>>(xhw, xlw, chw, clw, mask, train,
                                                   pk1, pk2, B, K, ncb);
    k_reduce2<<<B / 64, 256, 0, stream>>>(pk1, pk2, bestidx, fixlist, fixcnt, B, ncb);
    k_out    <<<B / 4, 256, 0, stream>>>(out_xn, cbw, bestidx, out, B);
    k_fix    <<<256, 256, 0, stream>>>(out_xn, cbw, mask, train, fixlist, fixcnt,
                                       out, B, K);
}